// Round 4
// baseline (145.005 us; speedup 1.0000x reference)
//
#include <hip/hip_runtime.h>
#include <hip/hip_bf16.h>
#include <float.h>

// Problem constants (from reference setup_inputs)
#define B_  4
#define C_  256
#define H_  50
#define W_  50
#define R_  300
#define PH_ 7
#define PW_ 7
#define S_  (H_ * W_)        // 2500 spatial positions
#define Q_  (PH_ * PW_)      // 49 bins per ROI

#define CQ_  64              // channels per pool block
#define NCQ  (C_ / CQ_)      // 4 channel-quarters
#define NWG2 (R_ * NCQ)      // 1200 pool blocks (divisible by 8 XCDs)

// ---------------------------------------------------------------------------
// Kernel T1: transpose fm [B, C, S] -> fmT [B, S, C].  64x64 LDS tiles.
// ---------------------------------------------------------------------------
__global__ __launch_bounds__(256) void transpose_fm(
    const float* __restrict__ fm,   // [B, C, S]
    float* __restrict__ fmT)        // [B, S, C]
{
    __shared__ float tile[64][65];

    const int b  = blockIdx.z;
    const int c0 = blockIdx.y * 64;           // 256/64 = 4 exact
    const int s0 = blockIdx.x * 64;           // ceil(2500/64) = 40

    const int tx = threadIdx.x;               // 0..63
    const int ty = threadIdx.y;               // 0..3

    // load: lanes along S (coalesced)
    {
        const int s = s0 + tx;
        if (s < S_) {
            #pragma unroll
            for (int j = 0; j < 16; ++j) {
                const int c = c0 + ty + j * 4;            // < 256 always
                tile[ty + j * 4][tx] = fm[((size_t)b * C_ + c) * S_ + s];
            }
        }
    }
    __syncthreads();

    // store: lanes along C (coalesced)
    {
        #pragma unroll
        for (int j = 0; j < 16; ++j) {
            const int s = s0 + ty + j * 4;
            if (s < S_) {
                const int c = c0 + tx;
                fmT[((size_t)b * S_ + s) * C_ + c] = tile[tx][ty + j * 4];
            }
        }
    }
}

// ---------------------------------------------------------------------------
// Block-uniform ROI decode (SPATIAL_SCALE == 1.0); matches reference exactly.
// ---------------------------------------------------------------------------
__device__ __forceinline__ void roi_decode(const float* __restrict__ rois, int r,
                                           int& b, int& x0, int& y0,
                                           int& roi_w, int& roi_h)
{
    const float* rp = rois + r * 5;
    b = (int)rp[4];                          // trunc, matches astype(int32)
    // jnp.round == round-half-to-even == rintf
    x0      = (int)rintf(rp[0]);
    y0      = (int)rintf(rp[1]);
    int x1  = (int)rintf(rp[2]);
    int y1  = (int)rintf(rp[3]);
    x0 = min(max(x0, 0), W_ - 1);
    x1 = min(max(x1, 0), W_ - 1);
    y0 = min(max(y0, 0), H_ - 1);
    y1 = min(max(y1, 0), H_ - 1);
    x1 = max(x1, x0 + 1);
    y1 = max(y1, y0 + 1);
    roi_w = x1 - x0;                         // >= 1
    roi_h = y1 - y0;                         // >= 1
}

// ---------------------------------------------------------------------------
// Kernel P: block = (roi, 64-channel quarter). 256 threads = 4 waves.
// lane = channel (coalesced 256 B reads from fmT); waves stride-interleave
// the 49 bins; results staged in padded LDS [49][65] (bank = (q+c)%32,
// conflict-free both phases); final write is a block-exclusive, contiguous,
// fully-coalesced 12.5 KB region of out. No intermediate global buffer.
// ---------------------------------------------------------------------------
__global__ __launch_bounds__(256) void roi_pool_fused(
    const float* __restrict__ fmT,   // [B, S, C]
    const float* __restrict__ rois,  // [R, 5]
    float* __restrict__ out)         // [R, C, PH*PW]
{
    __shared__ float buf[Q_ * 65];           // 12740 B

    // XCD-chunked swizzle (NWG2 % 8 == 0 -> simple form is bijective):
    // all 4 quarters of an ROI + ~37 neighboring ROIs share one XCD's L2.
    const int bid = blockIdx.x;
    const int swz = (bid & 7) * (NWG2 / 8) + (bid >> 3);
    const int r   = swz >> 2;                // / NCQ
    const int c0  = (swz & (NCQ - 1)) * CQ_;

    const int t    = threadIdx.x;
    const int wv   = t >> 6;                 // wave id 0..3
    const int lane = t & 63;                 // channel within quarter

    int b, x0, y0, roi_w, roi_h;
    roi_decode(rois, r, b, x0, y0, roi_w, roi_h);

    const float* base = fmT + (size_t)b * (S_ * C_) + (c0 + lane);

    // each wave handles bins q = wv, wv+4, ... (13/12/12/12, balanced)
    for (int q = wv; q < Q_; q += 4) {
        const int ph = q / PW_;
        const int pw = q - ph * PW_;
        // adaptive bin: start = floor(i*len/7), end = ceil((i+1)*len/7)
        const int ws = x0 + (pw * roi_w) / PW_;
        const int we = x0 + ((pw + 1) * roi_w + PW_ - 1) / PW_;
        const int hs = y0 + (ph * roi_h) / PH_;
        const int he = y0 + ((ph + 1) * roi_h + PH_ - 1) / PH_;
        // positions < end are provably in [0, dim); reference clip is a no-op.

        float m = -FLT_MAX;
        for (int h = hs; h < he; ++h) {
            const float* rowp = base + (h * W_) * C_;
            for (int w = ws; w < we; ++w)
                m = fmaxf(m, rowp[w * C_]);
        }
        buf[q * 65 + lane] = m;
    }
    __syncthreads();

    // block-exclusive coalesced write: out[r, c0..c0+64, 0..49)
    float* outp = out + ((size_t)r * C_ + c0) * Q_;
    #pragma unroll
    for (int k = 0; k < 13; ++k) {           // ceil(64*49 / 256) = 13
        const int e = k * 256 + t;
        if (e < CQ_ * Q_) {
            const int cl = e / Q_;
            const int q  = e - cl * Q_;
            outp[e] = buf[q * 65 + cl];
        }
    }
}

// ---------------------------------------------------------------------------
// Fallback (ws too small for fmT): round-1 thread-per-output kernel.
// ---------------------------------------------------------------------------
__global__ __launch_bounds__(256) void roi_pool_naive(
    const float* __restrict__ fm,    // [B, C, H, W]
    const float* __restrict__ rois,
    float* __restrict__ out)
{
    const int total = R_ * C_ * Q_;
    int t = blockIdx.x * blockDim.x + threadIdx.x;
    if (t >= total) return;
    int q   = t % Q_;
    int tmp = t / Q_;
    int pw  = q % PW_;
    int ph  = q / PW_;
    int c   = tmp % C_;
    int r   = tmp / C_;

    int b, x0, y0, roi_w, roi_h;
    roi_decode(rois, r, b, x0, y0, roi_w, roi_h);

    const int ws = x0 + (pw * roi_w) / PW_;
    const int we = x0 + ((pw + 1) * roi_w + PW_ - 1) / PW_;
    const int hs = y0 + (ph * roi_h) / PH_;
    const int he = y0 + ((ph + 1) * roi_h + PH_ - 1) / PH_;

    const float* p = fm + ((size_t)(b * C_ + c)) * S_;
    float m = -FLT_MAX;
    for (int h = hs; h < he; ++h)
        for (int w = ws; w < we; ++w)
            m = fmaxf(m, p[h * W_ + w]);
    out[t] = m;
}

extern "C" void kernel_launch(void* const* d_in, const int* in_sizes, int n_in,
                              void* d_out, int out_size, void* d_ws, size_t ws_size,
                              hipStream_t stream)
{
    const float* fm   = (const float*)d_in[0];  // [4,256,50,50]
    const float* rois = (const float*)d_in[1];  // [300,5]
    float* out        = (float*)d_out;          // [300,256,7,7]

    const size_t FMT_BYTES = (size_t)B_ * S_ * C_ * sizeof(float);   // 10.24 MB

    if (ws_size >= FMT_BYTES) {
        float* fmT = (float*)d_ws;
        {
            dim3 grid((S_ + 63) / 64, C_ / 64, B_);   // (40, 4, 4)
            dim3 block(64, 4, 1);
            transpose_fm<<<grid, block, 0, stream>>>(fm, fmT);
        }
        roi_pool_fused<<<NWG2, 256, 0, stream>>>(fmT, rois, out);
    } else {
        const int total = R_ * C_ * Q_;
        roi_pool_naive<<<(total + 255) / 256, 256, 0, stream>>>(fm, rois, out);
    }
}

// Round 5
// 50.203 us; speedup vs baseline: 2.8884x; 2.8884x over previous
//
#include <hip/hip_runtime.h>
#include <hip/hip_bf16.h>
#include <float.h>

// Problem constants (from reference setup_inputs)
#define B_  4
#define C_  256
#define H_  50
#define W_  50
#define R_  300
#define PH_ 7
#define PW_ 7
#define S_  (H_ * W_)        // 2500 spatial positions
#define Q_  (PH_ * PW_)      // 49 bins per ROI
#define NWG_POOL (R_ * Q_)   // 14700
#define CQ_  64              // channels per reorder block
#define NCQ  (C_ / CQ_)      // 4
#define NWG_REORD (R_ * NCQ) // 1200 (divisible by 8)

// ---------------------------------------------------------------------------
// XCD-bijective block swizzle (m204 form; valid for any nwg). Hardware
// round-robins consecutive blockIdx across XCDs, so orig%8 == XCD id; this
// gives each XCD a CONTIGUOUS range of swizzled ids (same r-chunks in K2 and
// K3 land on the same XCD -> ws2 lines are produced and consumed by one L2).
// ---------------------------------------------------------------------------
__device__ __forceinline__ int xcd_swizzle(int orig, int nwg) {
    const int NXCD = 8;
    int xcd = orig % NXCD;
    int idx = orig / NXCD;
    int q   = nwg / NXCD;
    int rem = nwg % NXCD;
    int base = (xcd < rem) ? xcd * (q + 1) : rem * (q + 1) + (xcd - rem) * q;
    return base + idx;
}

// ---------------------------------------------------------------------------
// Kernel T1: transpose fm [B, C, S] -> fmT [B, S, C].  64x64 LDS tiles.
// ---------------------------------------------------------------------------
__global__ __launch_bounds__(256) void transpose_fm(
    const float* __restrict__ fm,   // [B, C, S]
    float* __restrict__ fmT)        // [B, S, C]
{
    __shared__ float tile[64][65];

    const int b  = blockIdx.z;
    const int c0 = blockIdx.y * 64;           // 256/64 = 4 exact
    const int s0 = blockIdx.x * 64;           // ceil(2500/64) = 40

    const int tx = threadIdx.x;               // 0..63
    const int ty = threadIdx.y;               // 0..3

    {
        const int s = s0 + tx;
        if (s < S_) {
            #pragma unroll
            for (int j = 0; j < 16; ++j) {
                const int c = c0 + ty + j * 4;
                tile[ty + j * 4][tx] = fm[((size_t)b * C_ + c) * S_ + s];
            }
        }
    }
    __syncthreads();
    {
        #pragma unroll
        for (int j = 0; j < 16; ++j) {
            const int s = s0 + ty + j * 4;
            if (s < S_) {
                const int c = c0 + tx;
                fmT[((size_t)b * S_ + s) * C_ + c] = tile[tx][ty + j * 4];
            }
        }
    }
}

// ---------------------------------------------------------------------------
// Block-uniform ROI decode (SPATIAL_SCALE == 1.0); matches reference exactly.
// ---------------------------------------------------------------------------
__device__ __forceinline__ void roi_decode(const float* __restrict__ rois, int r,
                                           int& b, int& x0, int& y0,
                                           int& roi_w, int& roi_h)
{
    const float* rp = rois + r * 5;
    b = (int)rp[4];                          // trunc, matches astype(int32)
    // jnp.round == round-half-to-even == rintf
    x0      = (int)rintf(rp[0]);
    y0      = (int)rintf(rp[1]);
    int x1  = (int)rintf(rp[2]);
    int y1  = (int)rintf(rp[3]);
    x0 = min(max(x0, 0), W_ - 1);
    x1 = min(max(x1, 0), W_ - 1);
    y0 = min(max(y0, 0), H_ - 1);
    y1 = min(max(y1, 0), H_ - 1);
    x1 = max(x1, x0 + 1);
    y1 = max(y1, y0 + 1);
    roi_w = x1 - x0;                         // >= 1
    roi_h = y1 - y0;                         // >= 1
}

// ---------------------------------------------------------------------------
// Kernel P: block = (r, q) [swizzled], lane = channel. One bin per block ->
// per-wave load chain is only ~5 loads (latency hidden by 57 waves/SIMD of
// TLP). Coalesced 1 KB reads; block-exclusive contiguous 1 KB write to ws2.
// ---------------------------------------------------------------------------
__global__ __launch_bounds__(256) void roi_pool_t(
    const float* __restrict__ fmT,   // [B, S, C]
    const float* __restrict__ rois,  // [R, 5]
    float* __restrict__ ws2)         // [R, Q, C]
{
    const int wg = xcd_swizzle(blockIdx.x, NWG_POOL);
    const int r  = wg / Q_;
    const int q  = wg - r * Q_;
    const int ph = q / PW_;
    const int pw = q - ph * PW_;
    const int c  = threadIdx.x;

    int b, x0, y0, roi_w, roi_h;
    roi_decode(rois, r, b, x0, y0, roi_w, roi_h);

    // adaptive bin: start = floor(i*len/7), end = ceil((i+1)*len/7)
    const int ws = x0 + (pw * roi_w) / PW_;
    const int we = x0 + ((pw + 1) * roi_w + PW_ - 1) / PW_;
    const int hs = y0 + (ph * roi_h) / PH_;
    const int he = y0 + ((ph + 1) * roi_h + PH_ - 1) / PH_;
    // positions < end are provably in [0, dim); reference clip is a no-op.

    const float* base = fmT + (size_t)b * (S_ * C_) + c;

    float m = -FLT_MAX;
    for (int h = hs; h < he; ++h) {
        const float* rowp = base + (h * W_) * C_;
        for (int w = ws; w < we; ++w)
            m = fmaxf(m, rowp[w * C_]);
    }

    ws2[(size_t)wg * C_ + c] = m;            // wg = r*Q + q -> [R, Q, C]
}

// ---------------------------------------------------------------------------
// Kernel K3: reorder ws2 [R, Q, C] -> out [R, C, Q].
// Block = (r, 64-channel quarter) -> 1200 blocks. Each wave does <=13
// INDEPENDENT unrolled 256 B loads (pipelined), LDS transpose (padded, bank
// = (q + c) % 32 conflict-free), block-exclusive coalesced 12.5 KB write.
// Same XCD swizzle as K2 -> ws2 read hits the producing XCD's L2.
// ---------------------------------------------------------------------------
__global__ __launch_bounds__(256) void out_reorder(
    const float* __restrict__ ws2,   // [R, Q, C]
    float* __restrict__ out)         // [R, C, Q]
{
    __shared__ float buf[Q_ * 65];

    const int bid = blockIdx.x;
    const int swz = (bid & 7) * (NWG_REORD / 8) + (bid >> 3);  // 1200 % 8 == 0
    const int r   = swz >> 2;
    const int c0  = (swz & (NCQ - 1)) * CQ_;

    const int t    = threadIdx.x;
    const int wv   = t >> 6;
    const int lane = t & 63;

    const size_t base = (size_t)r * (Q_ * C_);

    // load phase: wave wv handles q = wv, wv+4, ... (13 fixed iterations,
    // unrolled -> all loads issued back-to-back, fully pipelined)
    #pragma unroll
    for (int k = 0; k < 13; ++k) {
        const int q = wv + k * 4;
        if (q < Q_) {
            buf[q * 65 + lane] = ws2[base + (size_t)q * C_ + c0 + lane];
        }
    }
    __syncthreads();

    // store phase: out[r, c0..c0+64, 0..49) contiguous 12.5 KB
    float* outp = out + ((size_t)r * C_ + c0) * Q_;
    #pragma unroll
    for (int k = 0; k < 13; ++k) {
        const int e = k * 256 + t;
        if (e < CQ_ * Q_) {
            const int cl = e / Q_;
            const int q  = e - cl * Q_;
            outp[e] = buf[q * 65 + cl];
        }
    }
}

// ---------------------------------------------------------------------------
// Fallback A (ws fits fmT only): block per ROI, direct write.
// ---------------------------------------------------------------------------
__global__ __launch_bounds__(256) void roi_pool_direct(
    const float* __restrict__ fmT,   // [B, S, C]
    const float* __restrict__ rois,
    float* __restrict__ out)         // [R, C, Q]
{
    const int r = blockIdx.x;
    const int c = threadIdx.x;

    int b, x0, y0, roi_w, roi_h;
    roi_decode(rois, r, b, x0, y0, roi_w, roi_h);

    const float* basep = fmT + (size_t)b * (S_ * C_) + c;
    float* outp = out + ((size_t)r * C_ + c) * Q_;

    for (int ph = 0; ph < PH_; ++ph) {
        const int hs = y0 + (ph * roi_h) / PH_;
        const int he = y0 + ((ph + 1) * roi_h + PH_ - 1) / PH_;
        for (int pw = 0; pw < PW_; ++pw) {
            const int ws = x0 + (pw * roi_w) / PW_;
            const int we = x0 + ((pw + 1) * roi_w + PW_ - 1) / PW_;
            float m = -FLT_MAX;
            for (int h = hs; h < he; ++h) {
                const float* rowp = basep + (h * W_) * C_;
                for (int w = ws; w < we; ++w)
                    m = fmaxf(m, rowp[w * C_]);
            }
            outp[ph * PW_ + pw] = m;
        }
    }
}

// ---------------------------------------------------------------------------
// Fallback Z (no usable ws): round-1 thread-per-output kernel.
// ---------------------------------------------------------------------------
__global__ __launch_bounds__(256) void roi_pool_naive(
    const float* __restrict__ fm,    // [B, C, H, W]
    const float* __restrict__ rois,
    float* __restrict__ out)
{
    const int total = R_ * C_ * Q_;
    int t = blockIdx.x * blockDim.x + threadIdx.x;
    if (t >= total) return;
    int q   = t % Q_;
    int tmp = t / Q_;
    int pw  = q % PW_;
    int ph  = q / PW_;
    int c   = tmp % C_;
    int r   = tmp / C_;

    int b, x0, y0, roi_w, roi_h;
    roi_decode(rois, r, b, x0, y0, roi_w, roi_h);

    const int ws = x0 + (pw * roi_w) / PW_;
    const int we = x0 + ((pw + 1) * roi_w + PW_ - 1) / PW_;
    const int hs = y0 + (ph * roi_h) / PH_;
    const int he = y0 + ((ph + 1) * roi_h + PH_ - 1) / PH_;

    const float* p = fm + ((size_t)(b * C_ + c)) * S_;
    float m = -FLT_MAX;
    for (int h = hs; h < he; ++h)
        for (int w = ws; w < we; ++w)
            m = fmaxf(m, p[h * W_ + w]);
    out[t] = m;
}

extern "C" void kernel_launch(void* const* d_in, const int* in_sizes, int n_in,
                              void* d_out, int out_size, void* d_ws, size_t ws_size,
                              hipStream_t stream)
{
    const float* fm   = (const float*)d_in[0];  // [4,256,50,50]
    const float* rois = (const float*)d_in[1];  // [300,5]
    float* out        = (float*)d_out;          // [300,256,7,7]

    const size_t FMT_BYTES = (size_t)B_ * S_ * C_ * sizeof(float);   // 10.24 MB
    const size_t WS2_BYTES = (size_t)R_ * Q_ * C_ * sizeof(float);   // 15.05 MB

    if (ws_size >= FMT_BYTES) {
        float* fmT = (float*)d_ws;
        {
            dim3 grid((S_ + 63) / 64, C_ / 64, B_);   // (40, 4, 4)
            dim3 block(64, 4, 1);
            transpose_fm<<<grid, block, 0, stream>>>(fm, fmT);
        }
        if (ws_size >= FMT_BYTES + WS2_BYTES) {
            float* ws2 = (float*)((char*)d_ws + FMT_BYTES);
            roi_pool_t<<<NWG_POOL, 256, 0, stream>>>(fmT, rois, ws2);
            out_reorder<<<NWG_REORD, 256, 0, stream>>>(ws2, out);
        } else {
            roi_pool_direct<<<R_, 256, 0, stream>>>(fmT, rois, out);
        }
    } else {
        const int total = R_ * C_ * Q_;
        roi_pool_naive<<<(total + 255) / 256, 256, 0, stream>>>(fm, rois, out);
    }
}

// Round 7
// 42.470 us; speedup vs baseline: 3.4143x; 1.1821x over previous
//
#include <hip/hip_runtime.h>
#include <hip/hip_bf16.h>
#include <float.h>

// Problem constants (from reference setup_inputs)
#define B_  4
#define C_  256
#define H_  50
#define W_  50
#define R_  300
#define PH_ 7
#define PW_ 7
#define S_  (H_ * W_)        // 2500
#define Q_  (PH_ * PW_)      // 49
#define SC_ (S_ * C_)        // 640000 floats per batch image
#define CQ_  64              // channels per pool block
#define NCQ  (C_ / CQ_)      // 4
#define NWG_POOL (R_ * NCQ)  // 1200 (divisible by 8)

// ---------------------------------------------------------------------------
// Kernel K1: transpose fm [B,C,S] -> fmT [B,S,C] AND build the span-4 table
//   P4[b,s,c] = max over w..min(w+3, W-1) (row-clamped, same row) of fm
// 64 s-cols (+4 halo) x 64 channels per block. LDS stride 69 (odd) ->
// conflict-free on both the s-lane write phase and the c-lane read phase.
// rem-clamp guarantees we never read cross-row or uninitialized columns.
// ---------------------------------------------------------------------------
__global__ __launch_bounds__(256) void transpose_tables(
    const float* __restrict__ fm,   // [B, C, S]
    float* __restrict__ fmT,        // [B, S, C]
    float* __restrict__ P4)         // [B, S, C]
{
    __shared__ float tile[64][69];

    const int b  = blockIdx.z;
    const int c0 = blockIdx.y * 64;           // 256/64 = 4
    const int s0 = blockIdx.x * 64;           // ceil(2500/64) = 40

    const int tx = threadIdx.x;               // 0..63
    const int ty = threadIdx.y;               // 0..3

    // main load: lanes along s (coalesced)
    if (s0 + tx < S_) {
        #pragma unroll
        for (int j = 0; j < 16; ++j) {
            const int c = c0 + ty + j * 4;
            tile[ty + j * 4][tx] = fm[((size_t)b * C_ + c) * S_ + (s0 + tx)];
        }
    }
    // halo: 4 extra s-columns (used only for same-row w+1..w+3 neighbors)
    if (tx < 4 && s0 + 64 + tx < S_) {
        #pragma unroll
        for (int j = 0; j < 16; ++j) {
            const int c = c0 + ty + j * 4;
            tile[ty + j * 4][64 + tx] = fm[((size_t)b * C_ + c) * S_ + (s0 + 64 + tx)];
        }
    }
    __syncthreads();

    // compute + store: lanes along c (coalesced); s (and w) uniform per wave
    #pragma unroll
    for (int j = 0; j < 16; ++j) {
        const int s = s0 + ty + j * 4;
        if (s < S_) {
            const int ls = ty + j * 4;
            const int w  = s % W_;                        // uniform per wave
            const float v0 = tile[tx][ls];
            int rem = W_ - 1 - w;                         // valid same-row nbrs
            if (rem > 3) rem = 3;                         // span-4 table
            float p4 = v0;
            #pragma unroll
            for (int d = 1; d <= 3; ++d)
                if (d <= rem) p4 = fmaxf(p4, tile[tx][ls + d]);

            const size_t o = ((size_t)b * S_ + s) * C_ + (c0 + tx);
            fmT[o] = v0;
            P4[o]  = p4;
        }
    }
}

// ---------------------------------------------------------------------------
// Block-uniform ROI decode (SPATIAL_SCALE == 1.0); matches reference exactly.
// ---------------------------------------------------------------------------
__device__ __forceinline__ void roi_decode(const float* __restrict__ rois, int r,
                                           int& b, int& x0, int& y0,
                                           int& roi_w, int& roi_h)
{
    const float* rp = rois + r * 5;
    b = (int)rp[4];                          // trunc, matches astype(int32)
    // jnp.round == round-half-to-even == rintf
    x0      = (int)rintf(rp[0]);
    y0      = (int)rintf(rp[1]);
    int x1  = (int)rintf(rp[2]);
    int y1  = (int)rintf(rp[3]);
    x0 = min(max(x0, 0), W_ - 1);
    x1 = min(max(x1, 0), W_ - 1);
    y0 = min(max(y0, 0), H_ - 1);
    y1 = min(max(y1, 0), H_ - 1);
    x1 = max(x1, x0 + 1);
    y1 = max(y1, y0 + 1);
    roi_w = x1 - x0;                         // >= 1  (bin widths  <= 8)
    roi_h = y1 - y0;                         // >= 1  (bin heights <= 8)
}

// ---------------------------------------------------------------------------
// Kernel K2: fused pool. Block = (roi, 64-channel quarter) -> 1200 blocks,
// 4 waves; wave wv handles bins q = wv, wv+4, ...
// Per bin (all control wave-uniform):
//   ww >= 4 : two P4 anchors/row (anchor a covers a..a+3; ws+3 <= we-1 and
//             we-4 >= ws because 4 <= ww <= 8 -> exact union = window)
//   ww <  4 : the ww (<=3) raw fmT columns/row
// All loads (<= 24) are independent and unrolled -> one latency exposure.
// Result staged in padded LDS [49][65] (bank = (q+c)%32, conflict-free);
// final write is the block-exclusive contiguous 12.5 KB out[r, c0..c0+64, :].
// ---------------------------------------------------------------------------
__global__ __launch_bounds__(256) void roi_pool_tables(
    const float* __restrict__ fmT,   // [B, S, C]
    const float* __restrict__ P4,    // [B, S, C]
    const float* __restrict__ rois,  // [R, 5]
    float* __restrict__ out)         // [R, C, Q]
{
    __shared__ float buf[Q_ * 65];           // 12740 B

    // XCD-chunked swizzle (1200 % 8 == 0 -> bijective): all 4 quarters of an
    // ROI + neighbors share one XCD's L2 copy of that ROI's table lines.
    const int bid = blockIdx.x;
    const int swz = (bid & 7) * (NWG_POOL / 8) + (bid >> 3);
    const int r   = swz >> 2;
    const int c0  = (swz & (NCQ - 1)) * CQ_;

    const int t    = threadIdx.x;
    const int wv   = t >> 6;                 // wave 0..3
    const int lane = t & 63;                 // channel within quarter

    int b, x0, y0, roi_w, roi_h;
    roi_decode(rois, r, b, x0, y0, roi_w, roi_h);

    const size_t cL = (size_t)(c0 + lane);
    const size_t imgBase = (size_t)b * SC_;  // element offset of image b

    for (int k = 0; k < 13; ++k) {
        const int q = wv + k * 4;
        if (q < Q_) {                        // uniform
            const int ph = q / PW_;
            const int pw = q - ph * PW_;
            // adaptive bin edges (exact reference arithmetic)
            const int ws = x0 + (pw * roi_w) / PW_;
            const int we = x0 + ((pw + 1) * roi_w + PW_ - 1) / PW_;
            const int hs = y0 + (ph * roi_h) / PH_;
            const int he = y0 + ((ph + 1) * roi_h + PH_ - 1) / PH_;
            const int ww = we - ws;          // 1..8
            const int wh = he - hs;          // 1..8

            const size_t o0 = imgBase + (size_t)(hs * W_ + ws) * C_ + cL;

            float m = -FLT_MAX;
            if (ww >= 4) {                   // uniform branch
                const float* pa = P4 + o0;
                const float* pb = pa + (size_t)(ww - 4) * C_;   // we-4 anchor
                float va[8], vb[8];
                #pragma unroll
                for (int kh = 0; kh < 8; ++kh)
                    if (kh < wh) {
                        va[kh] = pa[(size_t)kh * (W_ * C_)];
                        vb[kh] = pb[(size_t)kh * (W_ * C_)];
                    }
                #pragma unroll
                for (int kh = 0; kh < 8; ++kh)
                    if (kh < wh) m = fmaxf(m, fmaxf(va[kh], vb[kh]));
            } else {
                const float* p0 = fmT + o0;
                float v[3][8];
                #pragma unroll
                for (int jw = 0; jw < 3; ++jw)
                    if (jw < ww) {
                        #pragma unroll
                        for (int kh = 0; kh < 8; ++kh)
                            if (kh < wh)
                                v[jw][kh] = p0[(size_t)(kh * W_ + jw) * C_];
                    }
                #pragma unroll
                for (int jw = 0; jw < 3; ++jw)
                    if (jw < ww) {
                        #pragma unroll
                        for (int kh = 0; kh < 8; ++kh)
                            if (kh < wh) m = fmaxf(m, v[jw][kh]);
                    }
            }
            buf[q * 65 + lane] = m;
        }
    }
    __syncthreads();

    // block-exclusive coalesced write: out[r, c0..c0+64, 0..49)
    float* outp = out + ((size_t)r * C_ + c0) * Q_;
    #pragma unroll
    for (int k = 0; k < 13; ++k) {
        const int e = k * 256 + t;
        if (e < CQ_ * Q_) {
            const int cl = e / Q_;
            const int q  = e - cl * Q_;
            outp[e] = buf[q * 65 + cl];
        }
    }
}

// ---------------------------------------------------------------------------
// Fallback (ws too small for the 2 tables): round-1 thread-per-output kernel
// (proven, 42.7 us).
// ---------------------------------------------------------------------------
__global__ __launch_bounds__(256) void roi_pool_naive(
    const float* __restrict__ fm,    // [B, C, H, W]
    const float* __restrict__ rois,
    float* __restrict__ out)
{
    const int total = R_ * C_ * Q_;
    int t = blockIdx.x * blockDim.x + threadIdx.x;
    if (t >= total) return;
    int q   = t % Q_;
    int tmp = t / Q_;
    int pw  = q % PW_;
    int ph  = q / PW_;
    int c   = tmp % C_;
    int r   = tmp / C_;

    int b, x0, y0, roi_w, roi_h;
    roi_decode(rois, r, b, x0, y0, roi_w, roi_h);

    const int ws = x0 + (pw * roi_w) / PW_;
    const int we = x0 + ((pw + 1) * roi_w + PW_ - 1) / PW_;
    const int hs = y0 + (ph * roi_h) / PH_;
    const int he = y0 + ((ph + 1) * roi_h + PH_ - 1) / PH_;

    const float* p = fm + ((size_t)(b * C_ + c)) * S_;
    float m = -FLT_MAX;
    for (int h = hs; h < he; ++h)
        for (int w = ws; w < we; ++w)
            m = fmaxf(m, p[h * W_ + w]);
    out[t] = m;
}

extern "C" void kernel_launch(void* const* d_in, const int* in_sizes, int n_in,
                              void* d_out, int out_size, void* d_ws, size_t ws_size,
                              hipStream_t stream)
{
    const float* fm   = (const float*)d_in[0];  // [4,256,50,50]
    const float* rois = (const float*)d_in[1];  // [300,5]
    float* out        = (float*)d_out;          // [300,256,7,7]

    const size_t ARR  = (size_t)B_ * SC_;                // 2,560,000 floats
    const size_t NEED = 2 * ARR * sizeof(float);         // 20.48 MB

    if (ws_size >= NEED) {
        float* fmT = (float*)d_ws;
        float* P4  = fmT + ARR;
        {
            dim3 grid((S_ + 63) / 64, C_ / 64, B_);      // (40, 4, 4)
            dim3 block(64, 4, 1);
            transpose_tables<<<grid, block, 0, stream>>>(fm, fmT, P4);
        }
        roi_pool_tables<<<NWG_POOL, 256, 0, stream>>>(fmT, P4, rois, out);
    } else {
        const int total = R_ * C_ * Q_;
        roi_pool_naive<<<(total + 255) / 256, 256, 0, stream>>>(fm, rois, out);
    }
}

// Round 8
// 33.724 us; speedup vs baseline: 4.2998x; 1.2593x over previous
//
#include <hip/hip_runtime.h>
#include <hip/hip_bf16.h>
#include <float.h>

// Problem constants (from reference setup_inputs)
#define B_  4
#define C_  256
#define H_  50
#define W_  50
#define R_  300
#define PH_ 7
#define PW_ 7
#define S_  (H_ * W_)        // 2500
#define Q_  (PH_ * PW_)      // 49
#define SC_ (S_ * C_)        // 640000 floats per batch image
#define CQ_  64              // channels per pool block
#define NCQ  (C_ / CQ_)      // 4
#define NWG_POOL (R_ * NCQ)  // 1200 (divisible by 8)

// ---------------------------------------------------------------------------
// Kernel K1: transpose fm [B,C,S] -> fmT [B,S,C] AND build span tables
//   P2[b,s,c] = max over w..min(w+1, W-1) (row-clamped) of fm
//   P4[b,s,c] = max over w..min(w+3, W-1) (row-clamped) of fm
// 64 s-cols (+4 halo) x 64 channels per block; LDS stride 69 (odd, conflict-
// free both phases). Row-clamp => never reads cross-row or invalid columns.
// ---------------------------------------------------------------------------
__global__ __launch_bounds__(256) void transpose_tables(
    const float* __restrict__ fm,   // [B, C, S]
    float* __restrict__ fmT,        // [B, S, C]
    float* __restrict__ P2,         // [B, S, C]
    float* __restrict__ P4)         // [B, S, C]
{
    __shared__ float tile[64][69];

    const int b  = blockIdx.z;
    const int c0 = blockIdx.y * 64;           // 256/64 = 4
    const int s0 = blockIdx.x * 64;           // ceil(2500/64) = 40

    const int tx = threadIdx.x;               // 0..63 (lane)
    const int ty = threadIdx.y;               // 0..3  (wave)

    if (s0 + tx < S_) {
        #pragma unroll
        for (int j = 0; j < 16; ++j) {
            const int c = c0 + ty + j * 4;
            tile[ty + j * 4][tx] = fm[((size_t)b * C_ + c) * S_ + (s0 + tx)];
        }
    }
    if (tx < 4 && s0 + 64 + tx < S_) {
        #pragma unroll
        for (int j = 0; j < 16; ++j) {
            const int c = c0 + ty + j * 4;
            tile[ty + j * 4][64 + tx] = fm[((size_t)b * C_ + c) * S_ + (s0 + 64 + tx)];
        }
    }
    __syncthreads();

    #pragma unroll
    for (int j = 0; j < 16; ++j) {
        const int s = s0 + ty + j * 4;
        if (s < S_) {
            const int ls  = ty + j * 4;
            const int w   = s % W_;                    // wave-uniform
            const int rem = W_ - 1 - w;                // valid same-row nbrs
            const float v0 = tile[tx][ls];
            float p2 = (rem >= 1) ? fmaxf(v0, tile[tx][ls + 1]) : v0;
            float p4 = p2;
            if (rem >= 2) p4 = fmaxf(p4, tile[tx][ls + 2]);
            if (rem >= 3) p4 = fmaxf(p4, tile[tx][ls + 3]);

            const size_t o = ((size_t)b * S_ + s) * C_ + (c0 + tx);
            fmT[o] = v0;
            P2[o]  = p2;
            P4[o]  = p4;
        }
    }
}

// ---------------------------------------------------------------------------
// Block-uniform ROI decode (SPATIAL_SCALE == 1.0); matches reference exactly.
// ---------------------------------------------------------------------------
__device__ __forceinline__ void roi_decode(const float* __restrict__ rois, int r,
                                           int& b, int& x0, int& y0,
                                           int& roi_w, int& roi_h)
{
    const float* rp = rois + r * 5;
    b = (int)rp[4];                          // trunc, matches astype(int32)
    // jnp.round == round-half-to-even == rintf
    x0      = (int)rintf(rp[0]);
    y0      = (int)rintf(rp[1]);
    int x1  = (int)rintf(rp[2]);
    int y1  = (int)rintf(rp[3]);
    x0 = min(max(x0, 0), W_ - 1);
    x1 = min(max(x1, 0), W_ - 1);
    y0 = min(max(y0, 0), H_ - 1);
    y1 = min(max(y1, 0), H_ - 1);
    x1 = max(x1, x0 + 1);
    y1 = max(y1, y0 + 1);
    roi_w = x1 - x0;                         // >= 1  (bin widths  <= 8)
    roi_h = y1 - y0;                         // >= 1  (bin heights <= 8)
}

// ---------------------------------------------------------------------------
// Branchless per-bin pooling, WH = block-uniform max bin height (template).
// Width via span tables: sp = 4/2/1 -> anchors ws and we-sp cover exactly
// [ws,we) (verified: ww=1 both=ws; ww=2,3 P2; 4<=ww<=8 P4, ws+3<=we-1 and
// we-4>=ws). Rows: min(hs+kh, he-1) clamp -> duplicates, max unchanged.
// Every bin = 2*WH independent loads + fmax tree, ZERO branches.
// Bin->wave: contiguous ranges w0:0-12, w1:13-24, w2:25-36, w3:37-48; the
// within-wave clamp re-computes the wave's own last bin (same LDS value,
// no cross-wave aliasing).
// ---------------------------------------------------------------------------
template<int WH>
__device__ __forceinline__ void pool_bins(
    const float* __restrict__ fmT, const float* __restrict__ P2,
    const float* __restrict__ P4, float* __restrict__ buf,
    int wv, int lane, size_t imgC,
    int x0, int y0, int roi_w, int roi_h)
{
    const int start = wv * 12 + (wv ? 1 : 0);
    const int qlast = wv * 12 + 12;

    #pragma unroll
    for (int k = 0; k < 13; ++k) {
        int q = start + k;
        q = (q > qlast) ? qlast : q;
        const int ph = q / PW_;
        const int pw = q - ph * PW_;
        const int ws = x0 + (pw * roi_w) / PW_;
        const int we = x0 + ((pw + 1) * roi_w + PW_ - 1) / PW_;
        const int hs = y0 + (ph * roi_h) / PH_;
        const int he = y0 + ((ph + 1) * roi_h + PH_ - 1) / PH_;
        const int ww = we - ws;              // 1..8

        const int sp = (ww >= 4) ? 4 : ((ww >= 2) ? 2 : 1);
        const float* tb = (ww >= 4) ? P4 : ((ww >= 2) ? P2 : fmT);
        const int colB = we - sp;

        float va[WH], vb[WH];
        #pragma unroll
        for (int kh = 0; kh < WH; ++kh) {
            int row = hs + kh;
            row = (row > he - 1) ? (he - 1) : row;        // clamp (in-window)
            const size_t ro = imgC + (size_t)(row * W_) * C_;
            va[kh] = tb[ro + (size_t)ws * C_];
            vb[kh] = tb[ro + (size_t)colB * C_];
        }
        float m = -FLT_MAX;
        #pragma unroll
        for (int kh = 0; kh < WH; ++kh)
            m = fmaxf(m, fmaxf(va[kh], vb[kh]));

        buf[q * 65 + lane] = m;
    }
}

// ---------------------------------------------------------------------------
// Kernel K2: fused pool. Block = (roi, 64-ch quarter) -> 1200 blocks, 4 waves.
// whmax (exact, block-uniform) selects a fully-unrolled instantiation.
// Staged in padded LDS [49][65]; block-exclusive contiguous 12.5 KB write.
// ---------------------------------------------------------------------------
__global__ __launch_bounds__(256) void roi_pool_tables(
    const float* __restrict__ fmT,   // [B, S, C]
    const float* __restrict__ P2,    // [B, S, C]
    const float* __restrict__ P4,    // [B, S, C]
    const float* __restrict__ rois,  // [R, 5]
    float* __restrict__ out)         // [R, C, Q]
{
    __shared__ float buf[Q_ * 65];           // 12740 B

    // XCD-chunked swizzle (1200 % 8 == 0 -> bijective)
    const int bid = blockIdx.x;
    const int swz = (bid & 7) * (NWG_POOL / 8) + (bid >> 3);
    const int r   = swz >> 2;
    const int c0  = (swz & (NCQ - 1)) * CQ_;

    const int t    = threadIdx.x;
    const int wv   = t >> 6;
    const int lane = t & 63;

    int b, x0, y0, roi_w, roi_h;
    roi_decode(rois, r, b, x0, y0, roi_w, roi_h);

    // exact block-uniform max bin height
    int whmax = 1;
    #pragma unroll
    for (int i = 0; i < PH_; ++i) {
        const int hs = (i * roi_h) / PH_;
        const int he = ((i + 1) * roi_h + PH_ - 1) / PH_;
        whmax = max(whmax, he - hs);
    }

    const size_t imgC = (size_t)b * SC_ + (size_t)(c0 + lane);

    switch (whmax) {                         // block-uniform dispatch
        case 1: pool_bins<1>(fmT, P2, P4, buf, wv, lane, imgC, x0, y0, roi_w, roi_h); break;
        case 2: pool_bins<2>(fmT, P2, P4, buf, wv, lane, imgC, x0, y0, roi_w, roi_h); break;
        case 3: pool_bins<3>(fmT, P2, P4, buf, wv, lane, imgC, x0, y0, roi_w, roi_h); break;
        case 4: pool_bins<4>(fmT, P2, P4, buf, wv, lane, imgC, x0, y0, roi_w, roi_h); break;
        case 5: pool_bins<5>(fmT, P2, P4, buf, wv, lane, imgC, x0, y0, roi_w, roi_h); break;
        case 6: pool_bins<6>(fmT, P2, P4, buf, wv, lane, imgC, x0, y0, roi_w, roi_h); break;
        case 7: pool_bins<7>(fmT, P2, P4, buf, wv, lane, imgC, x0, y0, roi_w, roi_h); break;
        default: pool_bins<8>(fmT, P2, P4, buf, wv, lane, imgC, x0, y0, roi_w, roi_h); break;
    }
    __syncthreads();

    // block-exclusive coalesced write: out[r, c0..c0+64, 0..49)
    float* outp = out + ((size_t)r * C_ + c0) * Q_;
    #pragma unroll
    for (int k = 0; k < 13; ++k) {
        const int e = k * 256 + t;
        if (e < CQ_ * Q_) {
            const int cl = e / Q_;
            const int q  = e - cl * Q_;
            outp[e] = buf[q * 65 + cl];
        }
    }
}

// ---------------------------------------------------------------------------
// Fallback (ws too small for the 3 tables): round-1 thread-per-output kernel
// (proven, 42.7 us).
// ---------------------------------------------------------------------------
__global__ __launch_bounds__(256) void roi_pool_naive(
    const float* __restrict__ fm,    // [B, C, H, W]
    const float* __restrict__ rois,
    float* __restrict__ out)
{
    const int total = R_ * C_ * Q_;
    int t = blockIdx.x * blockDim.x + threadIdx.x;
    if (t >= total) return;
    int q   = t % Q_;
    int tmp = t / Q_;
    int pw  = q % PW_;
    int ph  = q / PW_;
    int c   = tmp % C_;
    int r   = tmp / C_;

    int b, x0, y0, roi_w, roi_h;
    roi_decode(rois, r, b, x0, y0, roi_w, roi_h);

    const int ws = x0 + (pw * roi_w) / PW_;
    const int we = x0 + ((pw + 1) * roi_w + PW_ - 1) / PW_;
    const int hs = y0 + (ph * roi_h) / PH_;
    const int he = y0 + ((ph + 1) * roi_h + PH_ - 1) / PH_;

    const float* p = fm + ((size_t)(b * C_ + c)) * S_;
    float m = -FLT_MAX;
    for (int h = hs; h < he; ++h)
        for (int w = ws; w < we; ++w)
            m = fmaxf(m, p[h * W_ + w]);
    out[t] = m;
}

extern "C" void kernel_launch(void* const* d_in, const int* in_sizes, int n_in,
                              void* d_out, int out_size, void* d_ws, size_t ws_size,
                              hipStream_t stream)
{
    const float* fm   = (const float*)d_in[0];  // [4,256,50,50]
    const float* rois = (const float*)d_in[1];  // [300,5]
    float* out        = (float*)d_out;          // [300,256,7,7]

    const size_t ARR  = (size_t)B_ * SC_;                // 2,560,000 floats
    const size_t NEED = 3 * ARR * sizeof(float);         // 30.72 MB

    if (ws_size >= NEED) {
        float* fmT = (float*)d_ws;
        float* P2  = fmT + ARR;
        float* P4  = P2 + ARR;
        {
            dim3 grid((S_ + 63) / 64, C_ / 64, B_);      // (40, 4, 4)
            dim3 block(64, 4, 1);
            transpose_tables<<<grid, block, 0, stream>>>(fm, fmT, P2, P4);
        }
        roi_pool_tables<<<NWG_POOL, 256, 0, stream>>>(fmT, P2, P4, rois, out);
    } else {
        const int total = R_ * C_ * Q_;
        roi_pool_naive<<<(total + 255) / 256, 256, 0, stream>>>(fm, rois, out);
    }
}